// Round 11
// baseline (84.541 us; speedup 1.0000x reference)
//
#include <hip/hip_runtime.h>

#define KDIM    1200
#define NBITS   2400
#define BATCHN  16384
#define WPAD    24    // u64 words per packed row: 19 used + pad -> 192 B rows, 64B-aligned
#define ROWB    192   // bytes per packed row
#define NPAR    1200  // parity outputs (cols 1200..2399); cols 0..1199 are identity
#define ROWS    32    // batch rows per encode block

typedef int si16 __attribute__((ext_vector_type(16)));
typedef int si8  __attribute__((ext_vector_type(8)));

// ---------- pack m rows to bits (one wave per row) ----------
__global__ __launch_bounds__(256) void pack_rows_int(const int* __restrict__ src,
                                                     unsigned long long* __restrict__ dst) {
    int gtid = blockIdx.x * blockDim.x + threadIdx.x;
    int wave = gtid >> 6;
    int lane = gtid & 63;
    if (wave >= BATCHN) return;
    const int* row = src + (size_t)wave * KDIM;
    unsigned long long* orow = dst + (size_t)wave * WPAD;
    #pragma unroll
    for (int j = 0; j < WPAD; ++j) {
        int idx = j * 64 + lane;
        int v = (idx < KDIM) ? row[idx] : 0;
        unsigned long long mask = __ballot(v != 0);
        if (lane == 0) orow[j] = mask;
    }
}

// ---------- pack G parity rows (1200..2399) to bits ----------
__global__ __launch_bounds__(256) void pack_g(const float* __restrict__ G,
                                              unsigned long long* __restrict__ gp) {
    int gtid = blockIdx.x * blockDim.x + threadIdx.x;
    int wave = gtid >> 6;            // parity row index 0..1199
    int lane = gtid & 63;
    if (wave >= NPAR) return;
    const float* row = G + (size_t)(NPAR + wave) * KDIM;
    unsigned long long* orow = gp + (size_t)wave * WPAD;
    #pragma unroll
    for (int j = 0; j < WPAD; ++j) {
        int idx = j * 64 + lane;
        float v = (idx < KDIM) ? row[idx] : 0.0f;
        unsigned long long mask = __ballot(v != 0.0f);
        if (lane == 0) orow[j] = mask;
    }
}

// ---------- encode: m-row in SGPRs (scalar loads), g-row in VGPRs ----------
// grid = (5, BATCHN/ROWS); block covers 256 columns (of each half) x ROWS rows.
__global__ __launch_bounds__(256, 8) void ldpc_encode(const unsigned long long* __restrict__ mp,
                                                      const unsigned long long* __restrict__ gp,
                                                      float* __restrict__ out) {
    const int tid = threadIdx.x;
    const int bx  = blockIdx.x;
    const int n   = bx * 256 + tid;                  // column 0..1199 (both halves)
    const bool nv = (n < NPAR);

    // this lane's parity-G row, 38 meaningful dwords in VGPRs
    unsigned g[38];
    {
        const uint4* gr = (const uint4*)(gp + (size_t)(nv ? n : 0) * WPAD);
        #pragma unroll
        for (int j = 0; j < 9; ++j) {
            uint4 v = gr[j];
            g[4 * j]     = v.x;
            g[4 * j + 1] = v.y;
            g[4 * j + 2] = v.z;
            g[4 * j + 3] = v.w;
        }
        uint4 v9 = gr[9];
        g[36] = v9.x;
        g[37] = v9.y;
    }

    const int row0 = blockIdx.y * ROWS;
    const char* rp = (const char*)mp + (size_t)row0 * ROWB;     // block-uniform
    const unsigned idoff = (unsigned)((bx * 8 + (tid >> 5)) * 4); // id-dword byte off in row
    const unsigned shf   = tid & 31;
    float* ob = out + (size_t)row0 * NBITS;

    #pragma unroll 1
    for (int i = 0; i < ROWS; ++i) {
        si16 A, B; si8 C;
        // EARLY-CLOBBER (=&s) is required: outputs must not overlap the rp input,
        // otherwise load #1 clobbers the pointer used by loads #2/#3 (r10 crash).
        asm volatile("s_load_dwordx16 %0, %3, 0x0\n\t"
                     "s_load_dwordx16 %1, %3, 0x40\n\t"
                     "s_load_dwordx8  %2, %3, 0x80"
                     : "=&s"(A), "=&s"(B), "=&s"(C)
                     : "s"(rp));
        unsigned idb = *(const unsigned*)(rp + idoff);   // per-thread dword (8 B/wave, L2)
        // tie the wait to the loaded values: uses below depend on these outputs,
        // so the compiler cannot hoist the VALU above the waitcnt (rule #18 tying).
        asm volatile("s_waitcnt lgkmcnt(0)" : "+s"(A), "+s"(B), "+s"(C));

        unsigned p = 0;
        #define PR(x, y, i) p ^= (((unsigned)(x) & g[i]) ^ ((unsigned)(y) & g[(i) + 1]))
        PR(A[0],  A[1],  0);  PR(A[2],  A[3],  2);
        PR(A[4],  A[5],  4);  PR(A[6],  A[7],  6);
        PR(A[8],  A[9],  8);  PR(A[10], A[11], 10);
        PR(A[12], A[13], 12); PR(A[14], A[15], 14);
        PR(B[0],  B[1],  16); PR(B[2],  B[3],  18);
        PR(B[4],  B[5],  20); PR(B[6],  B[7],  22);
        PR(B[8],  B[9],  24); PR(B[10], B[11], 26);
        PR(B[12], B[13], 28); PR(B[14], B[15], 30);
        PR(C[0],  C[1],  32); PR(C[2],  C[3],  34);
        PR(C[4],  C[5],  36);
        #undef PR

        if (nv) {
            ob[n]        = __uint_as_float(0x3f800000u | ((idb >> shf) << 31));
            ob[NPAR + n] = __uint_as_float(0x3f800000u | ((unsigned)__popc(p) << 31));
        }

        rp += ROWB;
        ob += NBITS;
    }
}

// ---------- fallback (workspace too small): direct parity GEMM, no assumptions ----------
__global__ __launch_bounds__(256) void ldpc_naive(const int* __restrict__ m,
                                                  const float* __restrict__ G,
                                                  float* __restrict__ out) {
    long long idx = (long long)blockIdx.x * blockDim.x + threadIdx.x;
    if (idx >= (long long)BATCHN * NBITS) return;
    int b = (int)(idx / NBITS);
    int n = (int)(idx % NBITS);
    int acc = 0;
    const int*   mr = m + (size_t)b * KDIM;
    const float* gr = G + (size_t)n * KDIM;
    for (int k = 0; k < KDIM; ++k)
        acc ^= (mr[k] & (gr[k] != 0.0f ? 1 : 0));
    out[idx] = 1.0f - 2.0f * (float)acc;
}

extern "C" void kernel_launch(void* const* d_in, const int* in_sizes, int n_in,
                              void* d_out, int out_size, void* d_ws, size_t ws_size,
                              hipStream_t stream) {
    const int*   m = (const int*)d_in[0];    // [BATCHN, KDIM] int32 (0/1)
    const float* G = (const float*)d_in[1];  // [NBITS, KDIM]  f32   (0/1), top 1200x1200 = I
    float* out = (float*)d_out;              // [BATCHN, NBITS] f32

    const size_t need = ((size_t)BATCHN + NPAR) * WPAD * sizeof(unsigned long long); // ~3.4MB
    if (ws_size >= need) {
        unsigned long long* mp = (unsigned long long*)d_ws;
        unsigned long long* gp = mp + (size_t)BATCHN * WPAD;

        pack_g       <<<(NPAR * 64) / 256, 256, 0, stream>>>(G, gp);
        pack_rows_int<<<(BATCHN * 64) / 256, 256, 0, stream>>>(m, mp);

        dim3 grid((NPAR + 255) / 256, BATCHN / ROWS);   // (5, 512)
        ldpc_encode<<<grid, 256, 0, stream>>>(mp, gp, out);
    } else {
        long long total = (long long)BATCHN * NBITS;
        ldpc_naive<<<(int)((total + 255) / 256), 256, 0, stream>>>(m, G, out);
    }
}

// Round 12
// 82.232 us; speedup vs baseline: 1.0281x; 1.0281x over previous
//
#include <hip/hip_runtime.h>

#define KDIM    1200
#define NBITS   2400
#define BATCHN  16384
#define WPAD    24    // u64 words per packed row: 19 used + pad -> 192 B rows, 64B-aligned
#define ROWB    192   // bytes per packed row
#define NPAR    1200  // parity outputs (cols 1200..2399); cols 0..1199 are identity
#define ROWS    32    // batch rows per encode block

// ---------- pack m rows to bits (one wave per row) ----------
__global__ __launch_bounds__(256) void pack_rows_int(const int* __restrict__ src,
                                                     unsigned long long* __restrict__ dst) {
    int gtid = blockIdx.x * blockDim.x + threadIdx.x;
    int wave = gtid >> 6;
    int lane = gtid & 63;
    if (wave >= BATCHN) return;
    const int* row = src + (size_t)wave * KDIM;
    unsigned long long* orow = dst + (size_t)wave * WPAD;
    #pragma unroll
    for (int j = 0; j < WPAD; ++j) {
        int idx = j * 64 + lane;
        int v = (idx < KDIM) ? row[idx] : 0;
        unsigned long long mask = __ballot(v != 0);
        if (lane == 0) orow[j] = mask;
    }
}

// ---------- pack G parity rows (1200..2399) to bits ----------
__global__ __launch_bounds__(256) void pack_g(const float* __restrict__ G,
                                              unsigned long long* __restrict__ gp) {
    int gtid = blockIdx.x * blockDim.x + threadIdx.x;
    int wave = gtid >> 6;            // parity row index 0..1199
    int lane = gtid & 63;
    if (wave >= NPAR) return;
    const float* row = G + (size_t)(NPAR + wave) * KDIM;
    unsigned long long* orow = gp + (size_t)wave * WPAD;
    #pragma unroll
    for (int j = 0; j < WPAD; ++j) {
        int idx = j * 64 + lane;
        float v = (idx < KDIM) ? row[idx] : 0.0f;
        unsigned long long mask = __ballot(v != 0.0f);
        if (lane == 0) orow[j] = mask;
    }
}

// ---------- encode: m-row in SGPRs via constant-AS scalar loads ----------
// grid = (5, BATCHN/ROWS); block covers 256 columns (of each half) x ROWS rows.
// Row pointer is block-uniform -> AS(4) loads scalarize to s_load_dwordx16/x8.
typedef __attribute__((address_space(4))) const unsigned cu32;

__global__ __launch_bounds__(256, 4) void ldpc_encode(const unsigned long long* __restrict__ mp,
                                                      const unsigned long long* __restrict__ gp,
                                                      float* __restrict__ out) {
    const int tid  = threadIdx.x;
    const int lane = tid & 63, wv = tid >> 6;
    const int bx   = blockIdx.x;
    const int n    = bx * 256 + tid;                 // column 0..1199 (both halves)
    const bool nv  = (n < NPAR);

    // this lane's parity-G row, 38 meaningful dwords in VGPRs
    unsigned g[38];
    {
        const uint4* gr = (const uint4*)(gp + (size_t)(nv ? n : 0) * WPAD);
        #pragma unroll
        for (int j = 0; j < 9; ++j) {
            uint4 v = gr[j];
            g[4 * j]     = v.x;
            g[4 * j + 1] = v.y;
            g[4 * j + 2] = v.z;
            g[4 * j + 3] = v.w;
        }
        uint4 v9 = gr[9];
        g[36] = v9.x;
        g[37] = v9.y;
    }

    const int row0 = blockIdx.y * ROWS;
    cu32* rp = (cu32*)((const char*)mp + (size_t)row0 * ROWB);  // block-uniform, 64B-aligned
    const int ida = bx * 8 + wv * 2;                 // idb dword for lanes 0..31 / +1 for 32..63
    const unsigned shf = tid & 31;
    float* ob = out + (size_t)row0 * NBITS;

    #pragma unroll 2
    for (int i = 0; i < ROWS; ++i) {
        // uniform scalar reads: land in SGPRs (s_load), broadcast free across lanes
        unsigned t[38];
        #pragma unroll
        for (int j = 0; j < 38; ++j) t[j] = rp[j];

        // identity dword: 2 uniform values per wave, one per half-wave
        unsigned idb = (lane & 32) ? rp[ida + 1] : rp[ida];

        unsigned p = 0;
        #pragma unroll
        for (int j = 0; j < 19; ++j)
            p ^= (t[2 * j] & g[2 * j]) ^ (t[2 * j + 1] & g[2 * j + 1]);

        if (nv) {
            ob[n]        = __uint_as_float(0x3f800000u | ((idb >> shf) << 31));
            ob[NPAR + n] = __uint_as_float(0x3f800000u | ((unsigned)__popc(p) << 31));
        }

        rp += ROWB / 4;
        ob += NBITS;
    }
}

// ---------- fallback (workspace too small): direct parity GEMM, no assumptions ----------
__global__ __launch_bounds__(256) void ldpc_naive(const int* __restrict__ m,
                                                  const float* __restrict__ G,
                                                  float* __restrict__ out) {
    long long idx = (long long)blockIdx.x * blockDim.x + threadIdx.x;
    if (idx >= (long long)BATCHN * NBITS) return;
    int b = (int)(idx / NBITS);
    int n = (int)(idx % NBITS);
    int acc = 0;
    const int*   mr = m + (size_t)b * KDIM;
    const float* gr = G + (size_t)n * KDIM;
    for (int k = 0; k < KDIM; ++k)
        acc ^= (mr[k] & (gr[k] != 0.0f ? 1 : 0));
    out[idx] = 1.0f - 2.0f * (float)acc;
}

extern "C" void kernel_launch(void* const* d_in, const int* in_sizes, int n_in,
                              void* d_out, int out_size, void* d_ws, size_t ws_size,
                              hipStream_t stream) {
    const int*   m = (const int*)d_in[0];    // [BATCHN, KDIM] int32 (0/1)
    const float* G = (const float*)d_in[1];  // [NBITS, KDIM]  f32   (0/1), top 1200x1200 = I
    float* out = (float*)d_out;              // [BATCHN, NBITS] f32

    const size_t need = ((size_t)BATCHN + NPAR) * WPAD * sizeof(unsigned long long); // ~3.4MB
    if (ws_size >= need) {
        unsigned long long* mp = (unsigned long long*)d_ws;
        unsigned long long* gp = mp + (size_t)BATCHN * WPAD;

        pack_g       <<<(NPAR * 64) / 256, 256, 0, stream>>>(G, gp);
        pack_rows_int<<<(BATCHN * 64) / 256, 256, 0, stream>>>(m, mp);

        dim3 grid((NPAR + 255) / 256, BATCHN / ROWS);   // (5, 512)
        ldpc_encode<<<grid, 256, 0, stream>>>(mp, gp, out);
    } else {
        long long total = (long long)BATCHN * NBITS;
        ldpc_naive<<<(int)((total + 255) / 256), 256, 0, stream>>>(m, G, out);
    }
}

// Round 13
// 77.952 us; speedup vs baseline: 1.0845x; 1.0549x over previous
//
#include <hip/hip_runtime.h>

#define KDIM    1200
#define NBITS   2400
#define BATCHN  16384
#define WPAD    24    // u64 words per packed row: 19 used + pad -> 192 B rows, 64B-aligned
#define ROWB    192   // bytes per packed row
#define NPAR    1200  // parity outputs (cols 1200..2399); cols 0..1199 are identity
#define ROWS    32    // batch rows per encode block

typedef int si16 __attribute__((ext_vector_type(16)));
typedef int si8  __attribute__((ext_vector_type(8)));

// ---------- pack m rows to bits (one wave per row) ----------
__global__ __launch_bounds__(256) void pack_rows_int(const int* __restrict__ src,
                                                     unsigned long long* __restrict__ dst) {
    int gtid = blockIdx.x * blockDim.x + threadIdx.x;
    int wave = gtid >> 6;
    int lane = gtid & 63;
    if (wave >= BATCHN) return;
    const int* row = src + (size_t)wave * KDIM;
    unsigned long long* orow = dst + (size_t)wave * WPAD;
    #pragma unroll
    for (int j = 0; j < WPAD; ++j) {
        int idx = j * 64 + lane;
        int v = (idx < KDIM) ? row[idx] : 0;
        unsigned long long mask = __ballot(v != 0);
        if (lane == 0) orow[j] = mask;
    }
}

// ---------- pack G parity rows (1200..2399) to bits ----------
__global__ __launch_bounds__(256) void pack_g(const float* __restrict__ G,
                                              unsigned long long* __restrict__ gp) {
    int gtid = blockIdx.x * blockDim.x + threadIdx.x;
    int wave = gtid >> 6;            // parity row index 0..1199
    int lane = gtid & 63;
    if (wave >= NPAR) return;
    const float* row = G + (size_t)(NPAR + wave) * KDIM;
    unsigned long long* orow = gp + (size_t)wave * WPAD;
    #pragma unroll
    for (int j = 0; j < WPAD; ++j) {
        int idx = j * 64 + lane;
        float v = (idx < KDIM) ? row[idx] : 0.0f;
        unsigned long long mask = __ballot(v != 0.0f);
        if (lane == 0) orow[j] = mask;
    }
}

// ---------- encode: m-row in SGPRs (asm s_load), 2 adjacent cols/lane ----------
// grid = (5, BATCHN/ROWS), block = 128 threads (2 waves) covering 256 columns
// of each half x ROWS batch rows.
__global__ void ldpc_encode(const unsigned long long* __restrict__ mp,
                            const unsigned long long* __restrict__ gp,
                            float* __restrict__ out) {
    const int tid = threadIdx.x;                     // 0..127
    const int bx  = blockIdx.x;                      // 0..4
    const int n0  = bx * 256 + 2 * tid;              // even column; owns n0, n0+1
    const bool nv = (n0 < NPAR);                     // n0 even, NPAR even -> pair-valid flag

    // two parity-G rows in VGPRs (2 x 38 dwords)
    unsigned g0[38], g1[38];
    {
        const uint4* gr0 = (const uint4*)(gp + (size_t)(nv ? n0 : 0) * WPAD);
        const uint4* gr1 = (const uint4*)(gp + (size_t)(nv ? n0 + 1 : 0) * WPAD);
        #pragma unroll
        for (int j = 0; j < 9; ++j) {
            uint4 a = gr0[j], b = gr1[j];
            g0[4 * j] = a.x; g0[4 * j + 1] = a.y; g0[4 * j + 2] = a.z; g0[4 * j + 3] = a.w;
            g1[4 * j] = b.x; g1[4 * j + 1] = b.y; g1[4 * j + 2] = b.z; g1[4 * j + 3] = b.w;
        }
        uint4 a9 = gr0[9], b9 = gr1[9];
        g0[36] = a9.x; g0[37] = a9.y;
        g1[36] = b9.x; g1[37] = b9.y;
    }

    const int row0 = blockIdx.y * ROWS;
    const char* rp = (const char*)mp + (size_t)row0 * ROWB;       // block-uniform
    // per-thread identity dword: global (vmcnt-only) load, decoupled from lgkm wait
    const unsigned* __restrict__ idp =
        (const unsigned*)mp + (size_t)row0 * (ROWB / 4) + (n0 >> 5);
    const unsigned shf = (unsigned)(n0 & 31);        // even; bit for n0, +1 for n0+1
    float2* ob_id = (float2*)(out + (size_t)row0 * NBITS + n0);
    float2* ob_pa = (float2*)(out + (size_t)row0 * NBITS + NPAR + n0);

    #pragma unroll 1
    for (int i = 0; i < ROWS; ++i) {
        si16 A, B; si8 C;
        // EARLY-CLOBBER outputs: must not alias rp input (r10 crash lesson).
        asm volatile("s_load_dwordx16 %0, %3, 0x0\n\t"
                     "s_load_dwordx16 %1, %3, 0x40\n\t"
                     "s_load_dwordx8  %2, %3, 0x80"
                     : "=&s"(A), "=&s"(B), "=&s"(C)
                     : "s"(rp));
        unsigned idb = *idp;                          // global_load_dword, vmcnt only
        // tie the wait to the loaded values so consumers can't hoist above it
        asm volatile("s_waitcnt lgkmcnt(0)" : "+s"(A), "+s"(B), "+s"(C));

        unsigned p0 = 0, p1 = 0;
        #define PR(x, y, i)                                                  \
            p0 ^= ((unsigned)(x) & g0[i]) ^ ((unsigned)(y) & g0[(i) + 1]);   \
            p1 ^= ((unsigned)(x) & g1[i]) ^ ((unsigned)(y) & g1[(i) + 1]);
        PR(A[0],  A[1],  0);  PR(A[2],  A[3],  2);
        PR(A[4],  A[5],  4);  PR(A[6],  A[7],  6);
        PR(A[8],  A[9],  8);  PR(A[10], A[11], 10);
        PR(A[12], A[13], 12); PR(A[14], A[15], 14);
        PR(B[0],  B[1],  16); PR(B[2],  B[3],  18);
        PR(B[4],  B[5],  20); PR(B[6],  B[7],  22);
        PR(B[8],  B[9],  24); PR(B[10], B[11], 26);
        PR(B[12], B[13], 28); PR(B[14], B[15], 30);
        PR(C[0],  C[1],  32); PR(C[2],  C[3],  34);
        PR(C[4],  C[5],  36);
        #undef PR

        if (nv) {
            float2 fi, fp;
            fi.x = __uint_as_float(0x3f800000u | (((idb >> shf) & 1u) << 31));
            fi.y = __uint_as_float(0x3f800000u | (((idb >> (shf + 1)) & 1u) << 31));
            fp.x = __uint_as_float(0x3f800000u | ((unsigned)__popc(p0) << 31));
            fp.y = __uint_as_float(0x3f800000u | ((unsigned)__popc(p1) << 31));
            *ob_id = fi;
            *ob_pa = fp;
        }

        rp += ROWB;
        idp += ROWB / 4;
        ob_id += NBITS / 2;
        ob_pa += NBITS / 2;
    }
}

// ---------- fallback (workspace too small): direct parity GEMM, no assumptions ----------
__global__ __launch_bounds__(256) void ldpc_naive(const int* __restrict__ m,
                                                  const float* __restrict__ G,
                                                  float* __restrict__ out) {
    long long idx = (long long)blockIdx.x * blockDim.x + threadIdx.x;
    if (idx >= (long long)BATCHN * NBITS) return;
    int b = (int)(idx / NBITS);
    int n = (int)(idx % NBITS);
    int acc = 0;
    const int*   mr = m + (size_t)b * KDIM;
    const float* gr = G + (size_t)n * KDIM;
    for (int k = 0; k < KDIM; ++k)
        acc ^= (mr[k] & (gr[k] != 0.0f ? 1 : 0));
    out[idx] = 1.0f - 2.0f * (float)acc;
}

extern "C" void kernel_launch(void* const* d_in, const int* in_sizes, int n_in,
                              void* d_out, int out_size, void* d_ws, size_t ws_size,
                              hipStream_t stream) {
    const int*   m = (const int*)d_in[0];    // [BATCHN, KDIM] int32 (0/1)
    const float* G = (const float*)d_in[1];  // [NBITS, KDIM]  f32   (0/1), top 1200x1200 = I
    float* out = (float*)d_out;              // [BATCHN, NBITS] f32

    const size_t need = ((size_t)BATCHN + NPAR) * WPAD * sizeof(unsigned long long); // ~3.4MB
    if (ws_size >= need) {
        unsigned long long* mp = (unsigned long long*)d_ws;
        unsigned long long* gp = mp + (size_t)BATCHN * WPAD;

        pack_g       <<<(NPAR * 64) / 256, 256, 0, stream>>>(G, gp);
        pack_rows_int<<<(BATCHN * 64) / 256, 256, 0, stream>>>(m, mp);

        dim3 grid(5, BATCHN / ROWS);                  // (5, 512), 128-thread blocks
        ldpc_encode<<<grid, 128, 0, stream>>>(mp, gp, out);
    } else {
        long long total = (long long)BATCHN * NBITS;
        ldpc_naive<<<(int)((total + 255) / 256), 256, 0, stream>>>(m, G, out);
    }
}